// Round 4
// baseline (141.431 us; speedup 1.0000x reference)
//
#include <hip/hip_runtime.h>

#define CUBIC_A (-0.75f)

typedef float f4nt __attribute__((ext_vector_type(4)));

__device__ __forceinline__ void nt_store4(float4* p, float4 v) {
    f4nt t;
    t.x = v.x; t.y = v.y; t.z = v.z; t.w = v.w;
    __builtin_nontemporal_store(t, (f4nt*)p);
}

__device__ __forceinline__ float cubic_w(float d) {
    float ad = fabsf(d);
    if (ad <= 1.0f) return ((CUBIC_A + 2.0f) * ad - (CUBIC_A + 3.0f)) * ad * ad + 1.0f;
    if (ad < 2.0f)  return CUBIC_A * (((ad - 5.0f) * ad + 8.0f) * ad - 4.0f);
    return 0.0f;
}

__device__ __forceinline__ float4 bicubic_pe(const float4* __restrict__ wgt,
                                             int px, int out_hw, int d4) {
    const int i = px / out_hw;
    const int j = px % out_hw;
    const float scale = 64.0f / (float)out_hw;
    const float si = ((float)i + 0.5f) * scale - 0.5f;
    const float sj = ((float)j + 0.5f) * scale - 0.5f;
    const int i0 = (int)floorf(si);
    const int j0 = (int)floorf(sj);
    int ih[4], iw[4];
    float wh[4], ww[4];
#pragma unroll
    for (int a = 0; a < 4; ++a) {
        int tp = i0 - 1 + a;
        wh[a] = cubic_w(si - (float)tp);
        ih[a] = min(63, max(0, tp));
        tp = j0 - 1 + a;
        ww[a] = cubic_w(sj - (float)tp);
        iw[a] = min(63, max(0, tp));
    }
    float ax = 0.f, ay = 0.f, az = 0.f, aw = 0.f;
#pragma unroll
    for (int a = 0; a < 4; ++a) {
        float rx = 0.f, ry = 0.f, rz = 0.f, rw = 0.f;
#pragma unroll
        for (int c = 0; c < 4; ++c) {
            const float4 v = wgt[(size_t)(ih[a] * 64 + iw[c]) * 256 + d4];
            rx = fmaf(ww[c], v.x, rx);
            ry = fmaf(ww[c], v.y, ry);
            rz = fmaf(ww[c], v.z, rz);
            rw = fmaf(ww[c], v.w, rw);
        }
        ax = fmaf(wh[a], rx, ax);
        ay = fmaf(wh[a], ry, ay);
        az = fmaf(wh[a], rz, az);
        aw = fmaf(wh[a], rw, aw);
    }
    return make_float4(ax, ay, az, aw);
}

// GRIDS = [(8,32,32),(8,48,48),(4,64,64),(1,64,64)] -> rows:
// [0,8192) g0 | [8192,26624) g1 | [26624,43008) g2 | [43008,47104) g3
// One block per OUTPUT ROW (47104 blocks x 256 threads). Per wave: no loops,
// x-load issued first, all loads independent -> MLP from wave count.
__global__ __launch_bounds__(256) void posemb_add_kernel(
    const float4* __restrict__ x,     // (47104, 256) as float4
    const float4* __restrict__ wgt,   // (64*64, 256) as float4
    const float4* __restrict__ tw,    // (16, 256) as float4
    float4* __restrict__ out)         // (47104, 256) as float4
{
    const int row = blockIdx.x;
    const int d4  = threadIdx.x;

    const size_t e = (size_t)row * 256 + d4;
    const float4 xv = x[e];           // issue the HBM-latency load first

    float4 pe;
    float4 tv = make_float4(0.f, 0.f, 0.f, 0.f);

    if (row < 8192) {                       // (8,32,32), interp
        const int f  = row >> 10;
        const int px = row & 1023;
        tv = tw[(size_t)f * 256 + d4];
        pe = bicubic_pe(wgt, px, 32, d4);
    } else if (row < 26624) {               // (8,48,48), interp
        const int r  = row - 8192;
        const int f  = r / 2304;            // magic-mul const div
        const int px = r - f * 2304;
        tv = tw[(size_t)f * 256 + d4];
        pe = bicubic_pe(wgt, px, 48, d4);
    } else if (row < 43008) {               // (4,64,64), direct
        const int r  = row - 26624;
        const int f  = r >> 12;
        const int px = r & 4095;
        tv = tw[(size_t)f * 256 + d4];
        pe = wgt[(size_t)px * 256 + d4];
    } else {                                // (1,64,64), direct, no time emb
        const int px = row - 43008;
        pe = wgt[(size_t)px * 256 + d4];
    }

    nt_store4(&((float4*)out)[e],
              make_float4(xv.x + pe.x + tv.x,
                          xv.y + pe.y + tv.y,
                          xv.z + pe.z + tv.z,
                          xv.w + pe.w + tv.w));
}

extern "C" void kernel_launch(void* const* d_in, const int* in_sizes, int n_in,
                              void* d_out, int out_size, void* d_ws, size_t ws_size,
                              hipStream_t stream) {
    const float4* x   = (const float4*)d_in[0];
    const float4* wgt = (const float4*)d_in[1];
    const float4* tw  = (const float4*)d_in[2];
    float4* out = (float4*)d_out;
    posemb_add_kernel<<<47104, 256, 0, stream>>>(x, wgt, tw, out);
}

// Round 5
// 83.455 us; speedup vs baseline: 1.6947x; 1.6947x over previous
//
#include <hip/hip_runtime.h>

#define CUBIC_A (-0.75f)

typedef float f4nt __attribute__((ext_vector_type(4)));

__device__ __forceinline__ void nt_store4(float4* p, float4 v) {
    f4nt t;
    t.x = v.x; t.y = v.y; t.z = v.z; t.w = v.w;
    __builtin_nontemporal_store(t, (f4nt*)p);
}

__device__ __forceinline__ float cubic_w(float d) {
    float ad = fabsf(d);
    if (ad <= 1.0f) return ((CUBIC_A + 2.0f) * ad - (CUBIC_A + 3.0f)) * ad * ad + 1.0f;
    if (ad < 2.0f)  return CUBIC_A * (((ad - 5.0f) * ad + 8.0f) * ad - 4.0f);
    return 0.0f;
}

__device__ __forceinline__ float4 bicubic_pe(const float4* __restrict__ wgt,
                                             int px, int out_hw, int d4) {
    const int i = px / out_hw;
    const int j = px % out_hw;
    const float scale = 64.0f / (float)out_hw;
    const float si = ((float)i + 0.5f) * scale - 0.5f;
    const float sj = ((float)j + 0.5f) * scale - 0.5f;
    const int i0 = (int)floorf(si);
    const int j0 = (int)floorf(sj);
    int ih[4], iw[4];
    float wh[4], ww[4];
#pragma unroll
    for (int a = 0; a < 4; ++a) {
        int tp = i0 - 1 + a;
        wh[a] = cubic_w(si - (float)tp);
        ih[a] = min(63, max(0, tp));
        tp = j0 - 1 + a;
        ww[a] = cubic_w(sj - (float)tp);
        iw[a] = min(63, max(0, tp));
    }
    float ax = 0.f, ay = 0.f, az = 0.f, aw = 0.f;
#pragma unroll
    for (int a = 0; a < 4; ++a) {
        float rx = 0.f, ry = 0.f, rz = 0.f, rw = 0.f;
#pragma unroll
        for (int c = 0; c < 4; ++c) {
            const float4 v = wgt[(size_t)(ih[a] * 64 + iw[c]) * 256 + d4];
            rx = fmaf(ww[c], v.x, rx);
            ry = fmaf(ww[c], v.y, ry);
            rz = fmaf(ww[c], v.z, rz);
            rw = fmaf(ww[c], v.w, rw);
        }
        ax = fmaf(wh[a], rx, ax);
        ay = fmaf(wh[a], ry, ay);
        az = fmaf(wh[a], rz, az);
        aw = fmaf(wh[a], rw, aw);
    }
    return make_float4(ax, ay, az, aw);
}

// Kernel A: materialize interpolated pe rows for the two interp grids into ws.
// ws layout (float4 rows of 256): [0,1024) = g0 32x32 pixels, [1024,3328) = g1 48x48.
__global__ __launch_bounds__(256) void pe_build_kernel(
    const float4* __restrict__ wgt,   // (4096, 256)
    float4* __restrict__ pe_ws)       // (3328, 256)
{
    const int b  = blockIdx.x;
    const int d4 = threadIdx.x;
    float4 pe;
    if (b < 1024) pe = bicubic_pe(wgt, b, 32, d4);
    else          pe = bicubic_pe(wgt, b - 1024, 48, d4);
    pe_ws[(size_t)b * 256 + d4] = pe;   // regular store -> stays L2/L3-hot for kernel B
}

// Kernel B: pure streaming add. One block per output row (47104), no loops.
// rows: [0,8192) g0 | [8192,26624) g1 | [26624,43008) g2 | [43008,47104) g3
__global__ __launch_bounds__(256) void posemb_add_kernel(
    const float4* __restrict__ x,     // (47104, 256)
    const float4* __restrict__ wgt,   // (4096, 256)
    const float4* __restrict__ tw,    // (16, 256)
    const float4* __restrict__ pe_ws, // (3328, 256)
    float4* __restrict__ out)         // (47104, 256)
{
    const int row = blockIdx.x;
    const int d4  = threadIdx.x;

    const size_t e = (size_t)row * 256 + d4;
    const float4 xv = x[e];           // longest-latency load first

    float4 pe;
    float4 tv = make_float4(0.f, 0.f, 0.f, 0.f);

    if (row < 8192) {                       // (8,32,32): table
        const int f  = row >> 10;
        const int px = row & 1023;
        tv = tw[(size_t)f * 256 + d4];
        pe = pe_ws[(size_t)px * 256 + d4];
    } else if (row < 26624) {               // (8,48,48): table
        const int r  = row - 8192;
        const int f  = r / 2304;
        const int px = r - f * 2304;
        tv = tw[(size_t)f * 256 + d4];
        pe = pe_ws[(size_t)(1024 + px) * 256 + d4];
    } else if (row < 43008) {               // (4,64,64): direct weight
        const int r  = row - 26624;
        const int f  = r >> 12;
        const int px = r & 4095;
        tv = tw[(size_t)f * 256 + d4];
        pe = wgt[(size_t)px * 256 + d4];
    } else {                                // (1,64,64): direct, no time emb
        const int px = row - 43008;
        pe = wgt[(size_t)px * 256 + d4];
    }

    nt_store4(&out[e], make_float4(xv.x + pe.x + tv.x,
                                   xv.y + pe.y + tv.y,
                                   xv.z + pe.z + tv.z,
                                   xv.w + pe.w + tv.w));
}

// Fallback (R3 structure, single kernel) if ws_size is too small.
template <int T>
__device__ __forceinline__ void add_frames(const float4* __restrict__ x,
                                           const float4* __restrict__ tw,
                                           float4* __restrict__ out,
                                           size_t rowbase, int ppf, int px, int d4,
                                           float4 pe) {
    const size_t base = (rowbase + (size_t)px) * 256 + d4;
    const size_t fstride = (size_t)ppf * 256;
#pragma unroll
    for (int f = 0; f < T; ++f) {
        const float4 xv = x[base + (size_t)f * fstride];
        float4 tv = make_float4(0.f, 0.f, 0.f, 0.f);
        if (T > 1) tv = tw[(size_t)f * 256 + d4];
        nt_store4(&out[base + (size_t)f * fstride],
                  make_float4(xv.x + pe.x + tv.x, xv.y + pe.y + tv.y,
                              xv.z + pe.z + tv.z, xv.w + pe.w + tv.w));
    }
}

__global__ __launch_bounds__(256) void posemb_fallback_kernel(
    const float4* __restrict__ x, const float4* __restrict__ wgt,
    const float4* __restrict__ tw, float4* __restrict__ out)
{
    const int b  = blockIdx.x;
    const int d4 = threadIdx.x;
    if (b < 1024) {
        const float4 pe = bicubic_pe(wgt, b, 32, d4);
        add_frames<8>(x, tw, out, 0, 1024, b, d4, pe);
    } else if (b < 3328) {
        const int px = b - 1024;
        const float4 pe = bicubic_pe(wgt, px, 48, d4);
        add_frames<8>(x, tw, out, 8192, 2304, px, d4, pe);
    } else if (b < 7424) {
        const int px = b - 3328;
        const float4 pe = wgt[(size_t)px * 256 + d4];
        add_frames<4>(x, tw, out, 26624, 4096, px, d4, pe);
    } else {
        const int px = b - 7424;
        const float4 pe = wgt[(size_t)px * 256 + d4];
        add_frames<1>(x, tw, out, 43008, 4096, px, d4, pe);
    }
}

extern "C" void kernel_launch(void* const* d_in, const int* in_sizes, int n_in,
                              void* d_out, int out_size, void* d_ws, size_t ws_size,
                              hipStream_t stream) {
    const float4* x   = (const float4*)d_in[0];
    const float4* wgt = (const float4*)d_in[1];
    const float4* tw  = (const float4*)d_in[2];
    float4* out = (float4*)d_out;

    const size_t pe_bytes = (size_t)3328 * 256 * sizeof(float4);  // 3.4 MB
    if (ws_size >= pe_bytes) {
        float4* pe_ws = (float4*)d_ws;
        pe_build_kernel<<<3328, 256, 0, stream>>>(wgt, pe_ws);
        posemb_add_kernel<<<47104, 256, 0, stream>>>(x, wgt, tw, pe_ws, out);
    } else {
        posemb_fallback_kernel<<<11520, 256, 0, stream>>>(x, wgt, tw, out);
    }
}